// Round 1
// baseline (1533.773 us; speedup 1.0000x reference)
//
#include <hip/hip_runtime.h>
#include <math.h>

// PAM module: B=4, C=256, H=W=64 -> N=4096, CK=C/8=32.
//
// Pipeline (all fp32 this round; compute-bound on PV GEMM, VALU path):
//   k1: QKV 1x1-conv projections  -> ws: Q[B][N][CK], Kt[B][N][CK], Vt[B][N][C]
//   k2: flash attention (online softmax over m), TR=32 rows/block, TM=32
//       -> ws: O[B][N][C]  (row-major in n, i.e. out^T)
//   k3: epilogue transpose: out[b][c][n] = gamma*O[b][n][c] + x[b][c][n]
//
// ws usage: (2*B*N*CK + 2*B*N*C) floats = 36 MB.

#define BB 4
#define CC 256
#define NN 4096
#define CKK 32

// ---------------- kernel 1: QKV projections ----------------
// q[b,n,o]  = sum_c Wq[o,c]*x[b,c,n] + bq[o]        (o < 32)
// kt[b,n,o] = sum_c Wk[o,c]*x[b,c,n] + bk[o]        (o < 32)
// vt[b,n,o] = sum_c Wv[o,c]*x[b,c,n] + bv[o]        (o < 256)
__global__ __launch_bounds__(256) void qkv_kernel(
    const float* __restrict__ x,
    const float* __restrict__ Wq, const float* __restrict__ bq,
    const float* __restrict__ Wk, const float* __restrict__ bk,
    const float* __restrict__ Wv, const float* __restrict__ bv,
    float* __restrict__ Q, float* __restrict__ K, float* __restrict__ V)
{
    __shared__ float xs[CC][36];           // 36 KB, padded (stride 36: 16B-aligned float4 rows)
    const int b  = blockIdx.y;
    const int n0 = blockIdx.x * 32;
    const int tid = threadIdx.x;

    // load x tile [256 c][32 n], coalesced over n
    const float* xb = x + (size_t)b * CC * NN + n0;
    for (int idx = tid; idx < CC * 32; idx += 256) {
        int c = idx >> 5, j = idx & 31;
        xs[c][j] = xb[(size_t)c * NN + j];
    }
    __syncthreads();

    const int ob = tid & 31;   // 32 parallel output channels
    const int jg = tid >> 5;   // 8 groups of 4 columns
    // 10 iterations cover 320 output channels (32 q + 32 k + 256 v)
    for (int oi = 0; oi < 10; ++oi) {
        const int o = oi * 32 + ob;
        const float* Wrow; float bias; float* dst; int oo; int ld;
        if (o < 32)       { Wrow = Wq + o * CC;        bias = bq[o];       dst = Q; oo = o;       ld = CKK; }
        else if (o < 64)  { Wrow = Wk + (o - 32) * CC; bias = bk[o - 32];  dst = K; oo = o - 32;  ld = CKK; }
        else              { Wrow = Wv + (o - 64) * CC; bias = bv[o - 64];  dst = V; oo = o - 64;  ld = CC;  }
        float a0 = 0.f, a1 = 0.f, a2 = 0.f, a3 = 0.f;
        #pragma unroll 4
        for (int c = 0; c < CC; ++c) {
            float w = Wrow[c];
            float4 xv = *(const float4*)&xs[c][jg * 4];
            a0 += w * xv.x; a1 += w * xv.y; a2 += w * xv.z; a3 += w * xv.w;
        }
        size_t base = ((size_t)b * NN + n0 + jg * 4) * ld + oo;
        dst[base]          = a0 + bias;   // lanes 0..31 contiguous in oo -> coalesced
        dst[base + ld]     = a1 + bias;
        dst[base + 2*ld]   = a2 + bias;
        dst[base + 3*ld]   = a3 + bias;
    }
}

// ---------------- kernel 2: flash attention ----------------
// S[n,m] = sum_o Q[n,o]*Kt[m,o]  (no scale), P = softmax_m(S), O[n,c] = sum_m P[n,m]*Vt[m,c]
__global__ __launch_bounds__(256) void attn_kernel(
    const float* __restrict__ Q, const float* __restrict__ K,
    const float* __restrict__ V, float* __restrict__ O)
{
    __shared__ float qs[32][36];
    __shared__ float ks[32][36];
    __shared__ float ps[32][36];
    // V tile: 8 groups of 32 floats, each group padded to 36 -> row stride 288.
    // element (m, c) at vs[m*288 + (c>>5)*36 + (c&31)]: cg-groups land on
    // distinct banks (4cg+4i), conflict-free b128 reads.
    __shared__ float vs[32 * 288];

    const int b   = blockIdx.y;
    const int n0  = blockIdx.x * 32;
    const int tid = threadIdx.x;
    const int r   = tid >> 3;        // query row 0..31 (this block's tile)
    const int cg  = tid & 7;         // col group: c0 = 32*cg
    const int c0  = cg * 32;

    const float* Qb = Q + ((size_t)b * NN + n0) * CKK;
    for (int idx = tid; idx < 32 * CKK; idx += 256)
        qs[idx >> 5][idx & 31] = Qb[idx];

    float acc[32];
    #pragma unroll
    for (int i = 0; i < 32; ++i) acc[i] = 0.f;
    float m_i = -INFINITY, l_i = 0.f;
    __syncthreads();

    for (int mt = 0; mt < NN / 32; ++mt) {
        const int m0 = mt * 32;
        const float* Kb = K + ((size_t)b * NN + m0) * CKK;
        for (int idx = tid; idx < 32 * CKK; idx += 256)
            ks[idx >> 5][idx & 31] = Kb[idx];
        const float* Vb = V + ((size_t)b * NN + m0) * CC;
        for (int idx = tid; idx < 32 * CC; idx += 256) {
            int m = idx >> 8, c = idx & 255;
            vs[m * 288 + (c >> 5) * 36 + (c & 31)] = Vb[idx];
        }
        __syncthreads();

        // S for (r, m = 4*cg + i), i=0..3
        float s[4];
        #pragma unroll
        for (int i = 0; i < 4; ++i) {
            const int m = cg * 4 + i;
            float as = 0.f;
            #pragma unroll
            for (int kk = 0; kk < 32; kk += 4) {
                float4 q4 = *(const float4*)&qs[r][kk];
                float4 k4 = *(const float4*)&ks[m][kk];
                as += q4.x*k4.x + q4.y*k4.y + q4.z*k4.z + q4.w*k4.w;
            }
            s[i] = as;
        }
        // wave-parallel online softmax: 8 lanes per row (consecutive lanes)
        float tmax = fmaxf(fmaxf(s[0], s[1]), fmaxf(s[2], s[3]));
        #pragma unroll
        for (int d = 1; d < 8; d <<= 1) tmax = fmaxf(tmax, __shfl_xor(tmax, d, 8));
        const float m_new = fmaxf(m_i, tmax);
        const float al = __expf(m_i - m_new);   // exp(-inf)=0 on first tile
        float psum = 0.f;
        #pragma unroll
        for (int i = 0; i < 4; ++i) {
            float p = __expf(s[i] - m_new);
            ps[r][cg * 4 + i] = p;
            psum += p;
        }
        #pragma unroll
        for (int d = 1; d < 8; d <<= 1) psum += __shfl_xor(psum, d, 8);
        l_i = l_i * al + psum;
        m_i = m_new;
        #pragma unroll
        for (int i = 0; i < 32; ++i) acc[i] *= al;
        __syncthreads();   // make ps visible (cheap safety; also orders vs reuse)

        // PV: acc[c] += P[r][m] * V[m][c0+c]
        #pragma unroll 4
        for (int m = 0; m < 32; ++m) {
            const float p = ps[r][m];
            const float* vrow = &vs[m * 288 + cg * 36];
            #pragma unroll
            for (int i = 0; i < 8; ++i) {
                float4 v4 = *(const float4*)&vrow[i * 4];
                acc[i*4+0] += p * v4.x;
                acc[i*4+1] += p * v4.y;
                acc[i*4+2] += p * v4.z;
                acc[i*4+3] += p * v4.w;
            }
        }
        __syncthreads();
    }

    const float inv_l = 1.f / l_i;
    float* Ob = O + ((size_t)b * NN + n0 + r) * CC + c0;
    #pragma unroll
    for (int i = 0; i < 32; ++i) Ob[i] = acc[i] * inv_l;
}

// ---------------- kernel 3: epilogue transpose + residual ----------------
__global__ __launch_bounds__(256) void epilogue_kernel(
    const float* __restrict__ O, const float* __restrict__ x,
    const float* __restrict__ gamma, float* __restrict__ out)
{
    __shared__ float t[32][33];
    const int b  = blockIdx.z;
    const int cb = blockIdx.y * 32;
    const int n0 = blockIdx.x * 32;
    const int tid = threadIdx.x;
    const float g = gamma[0];

    for (int idx = tid; idx < 1024; idx += 256) {
        int rr = idx >> 5, cc = idx & 31;
        t[rr][cc] = O[((size_t)b * NN + n0 + rr) * CC + cb + cc];
    }
    __syncthreads();
    for (int idx = tid; idx < 1024; idx += 256) {
        int cc = idx >> 5, rr = idx & 31;
        size_t off = ((size_t)b * CC + cb + cc) * NN + n0 + rr;
        out[off] = g * t[rr][cc] + x[off];
    }
}

extern "C" void kernel_launch(void* const* d_in, const int* in_sizes, int n_in,
                              void* d_out, int out_size, void* d_ws, size_t ws_size,
                              hipStream_t stream) {
    const float* x     = (const float*)d_in[0];
    const float* Wq    = (const float*)d_in[1];
    const float* bq    = (const float*)d_in[2];
    const float* Wk    = (const float*)d_in[3];
    const float* bk    = (const float*)d_in[4];
    const float* Wv    = (const float*)d_in[5];
    const float* bv    = (const float*)d_in[6];
    const float* gamma = (const float*)d_in[7];
    float* out = (float*)d_out;

    float* ws = (float*)d_ws;
    float* Q = ws;                       // [B][N][CK]  524288 floats
    float* K = ws + 524288;              // [B][N][CK]  524288 floats
    float* V = ws + 1048576;             // [B][N][C]   4194304 floats
    float* O = ws + 5242880;             // [B][N][C]   4194304 floats
    // total 9437184 floats = 36 MB of ws

    qkv_kernel<<<dim3(NN / 32, BB), 256, 0, stream>>>(x, Wq, bq, Wk, bk, Wv, bv, Q, K, V);
    attn_kernel<<<dim3(NN / 32, BB), 256, 0, stream>>>(Q, K, V, O);
    epilogue_kernel<<<dim3(NN / 32, CC / 32, BB), 256, 0, stream>>>(O, x, gamma, out);
}

// Round 2
// 202.562 us; speedup vs baseline: 7.5719x; 7.5719x over previous
//
#include <hip/hip_runtime.h>
#include <math.h>

// PAM module on MFMA: B=4, C=256, H=W=64 -> N=4096, CK=32.
// k0a: pack W -> bf16 [320][256] + bias[320]
// k0b: transpose x -> xT[b][n][c] bf16
// k1 : MFMA QKV: Q[b][n][32], K[b][m][32] (bf16), Vc[b][c][m] (bf16, transposed)
// k2 : MFMA flash attention -> O[b][n][c] fp32
// k3 : out[b][c][n] = gamma*O[b][n][c] + x[b][c][n]

#define BB 4
#define CC 256
#define NN 4096
#define CKK 32

typedef __attribute__((ext_vector_type(4))) float f32x4;
typedef __attribute__((ext_vector_type(8))) short short8;
typedef __attribute__((ext_vector_type(4))) short short4v;

static __device__ __forceinline__ ushort f2bf(float f) {
    union { float f; unsigned u; } v; v.f = f;
    unsigned r = v.u + 0x7FFFu + ((v.u >> 16) & 1u);
    return (ushort)(r >> 16);
}

// ---------------- k0a: pack weights + biases to bf16 ----------------
__global__ __launch_bounds__(256) void pack_w_kernel(
    const float* __restrict__ Wq, const float* __restrict__ bq,
    const float* __restrict__ Wk, const float* __restrict__ bk,
    const float* __restrict__ Wv, const float* __restrict__ bv,
    ushort* __restrict__ Wb, float* __restrict__ bias)
{
    const int o = blockIdx.x;      // 0..319
    const int c = threadIdx.x;     // 0..255
    const float* src; float bsc;
    if (o < 32)      { src = Wq + o * CC;        bsc = bq[o]; }
    else if (o < 64) { src = Wk + (o - 32) * CC; bsc = bk[o - 32]; }
    else             { src = Wv + (o - 64) * CC; bsc = bv[o - 64]; }
    Wb[o * CC + c] = f2bf(src[c]);
    if (c == 0) bias[o] = bsc;
}

// ---------------- k0b: x[b][c][n] fp32 -> xT[b][n][c] bf16 ----------------
__global__ __launch_bounds__(256) void xpose_kernel(
    const float* __restrict__ x, ushort* __restrict__ xT)
{
    __shared__ float t[32][33];
    const int b = blockIdx.z, c0 = blockIdx.y * 32, n0 = blockIdx.x * 32;
    const int tid = threadIdx.x;
    #pragma unroll
    for (int i = 0; i < 4; ++i) {
        int idx = tid + i * 256, rr = idx >> 5, nn = idx & 31;
        t[rr][nn] = x[((size_t)b * CC + c0 + rr) * NN + n0 + nn];
    }
    __syncthreads();
    #pragma unroll
    for (int i = 0; i < 4; ++i) {
        int idx = tid + i * 256, rr = idx >> 5, cc = idx & 31;
        xT[((size_t)b * NN + n0 + rr) * CC + c0 + cc] = f2bf(t[cc][rr]);
    }
}

// ---------------- k1: QKV projections via MFMA ----------------
// Out[o][n] = sum_c W[o][c]*x[c][n] + bias[o], per batch. 4 waves, each owns
// 80 output channels (5 16-chunks) x 64 n. A/B frags direct from global (L2).
__global__ __launch_bounds__(256) void qkv_mfma_kernel(
    const ushort* __restrict__ Wb, const float* __restrict__ bias,
    const ushort* __restrict__ xT,
    ushort* __restrict__ Q, ushort* __restrict__ Kt, ushort* __restrict__ V)
{
    const int b = blockIdx.y, n0 = blockIdx.x * 64;
    const int tid = threadIdx.x;
    const int w = tid >> 6, lane = tid & 63, l15 = lane & 15, q = lane >> 4;

    f32x4 acc[5][4];
    #pragma unroll
    for (int c5 = 0; c5 < 5; ++c5)
        #pragma unroll
        for (int nc = 0; nc < 4; ++nc) acc[c5][nc] = (f32x4)0.f;

    #pragma unroll
    for (int ks = 0; ks < 8; ++ks) {
        short8 af[5], bf[4];
        #pragma unroll
        for (int c5 = 0; c5 < 5; ++c5)
            af[c5] = *(const short8*)&Wb[(w * 80 + c5 * 16 + l15) * CC + ks * 32 + q * 8];
        #pragma unroll
        for (int nc = 0; nc < 4; ++nc)
            bf[nc] = *(const short8*)&xT[((size_t)b * NN + n0 + nc * 16 + l15) * CC + ks * 32 + q * 8];
        #pragma unroll
        for (int c5 = 0; c5 < 5; ++c5)
            #pragma unroll
            for (int nc = 0; nc < 4; ++nc)
                acc[c5][nc] = __builtin_amdgcn_mfma_f32_16x16x32_bf16(af[c5], bf[nc], acc[c5][nc], 0, 0, 0);
    }

    #pragma unroll
    for (int c5 = 0; c5 < 5; ++c5) {
        const int o0 = w * 80 + c5 * 16;
        float bia[4];
        #pragma unroll
        for (int r = 0; r < 4; ++r) bia[r] = bias[o0 + q * 4 + r];
        if (o0 >= 64) {
            // V rows -> Vc[b][c][n], lanes contiguous in n
            #pragma unroll
            for (int nc = 0; nc < 4; ++nc)
                #pragma unroll
                for (int r = 0; r < 4; ++r)
                    V[((size_t)b * CC + o0 - 64 + q * 4 + r) * NN + n0 + nc * 16 + l15] =
                        f2bf(acc[c5][nc][r] + bia[r]);
        } else {
            // Q/K rows -> [n][32] layout; each lane holds 4 contiguous o -> 8B store
            ushort* dst = (o0 < 32) ? Q : Kt;
            const int oo = (o0 & 31) + q * 4;
            #pragma unroll
            for (int nc = 0; nc < 4; ++nc) {
                short4v h;
                #pragma unroll
                for (int r = 0; r < 4; ++r) h[r] = (short)f2bf(acc[c5][nc][r] + bia[r]);
                *(short4v*)&dst[((size_t)b * NN + n0 + nc * 16 + l15) * CKK + oo] = h;
            }
        }
    }
}

// ---------------- k2: MFMA flash attention ----------------
// 4 waves x 16 query rows, KV tile 32, double-buffered LDS, reg-staged prefetch.
__global__ __launch_bounds__(256) void attn_mfma_kernel(
    const ushort* __restrict__ Q, const ushort* __restrict__ K,
    const ushort* __restrict__ V, float* __restrict__ O)
{
    __shared__ __align__(16) ushort kt[2][32][56];    // K tile [m][ck], stride 112B (2-way = free)
    __shared__ __align__(16) ushort vc[2][256][56];   // V tile [c][m], stride 112B
    __shared__ __align__(16) ushort pb[4][16][56];    // per-wave P tile [n][m]

    // XCD swizzle: batch b pinned to XCDs {2b,2b+1}; K+V (2.3MB) fits 4MB L2.
    const int id = blockIdx.x;            // 256 blocks, assume xcd = id % 8
    const int xcd = id & 7, ix = id >> 3;
    const int b = xcd >> 1;
    const int n0 = (((xcd & 1) << 5) + ix) * 64;

    const int tid = threadIdx.x;
    const int w = tid >> 6, lane = tid & 63, l15 = lane & 15, q = lane >> 4;

    // Q fragment (A): row = l15 (wave's 16 rows), k = q*8..+7
    short8 qf = *(const short8*)&Q[((size_t)b * NN + n0 + w * 16 + l15) * CKK + q * 8];

    f32x4 acc[16];
    #pragma unroll
    for (int i = 0; i < 16; ++i) acc[i] = (f32x4)0.f;
    float m_i[4] = {-1e30f, -1e30f, -1e30f, -1e30f};
    float l_p[4] = {0.f, 0.f, 0.f, 0.f};   // per-lane partial row-sums

    // staging assignment
    const int krow = tid >> 3, kseg = tid & 7;          // K: 32 rows x 8 segs of 8B
    const size_t kgbase = (size_t)b * NN * CKK;
    const size_t vgbase = (size_t)b * CC * NN;

    // prologue: tile 0
    short4v kreg = *(const short4v*)&K[kgbase + (size_t)krow * CKK + kseg * 4];
    short8 vreg[4];
    #pragma unroll
    for (int i = 0; i < 4; ++i) {
        int idx = tid + 256 * i, c = idx >> 2, seg = idx & 3;
        vreg[i] = *(const short8*)&V[vgbase + (size_t)c * NN + seg * 8];
    }
    *(short4v*)&kt[0][krow][kseg * 4] = kreg;
    #pragma unroll
    for (int i = 0; i < 4; ++i) {
        int idx = tid + 256 * i, c = idx >> 2, seg = idx & 3;
        *(short8*)&vc[0][c][seg * 8] = vreg[i];
    }
    __syncthreads();

    int cur = 0;
    for (int mt = 0; mt < NN / 32; ++mt) {
        // issue next tile's global loads (latency hides under compute)
        if (mt < NN / 32 - 1) {
            const int m0n = (mt + 1) * 32;
            kreg = *(const short4v*)&K[kgbase + (size_t)(m0n + krow) * CKK + kseg * 4];
            #pragma unroll
            for (int i = 0; i < 4; ++i) {
                int idx = tid + 256 * i, c = idx >> 2, seg = idx & 3;
                vreg[i] = *(const short8*)&V[vgbase + (size_t)c * NN + m0n + seg * 8];
            }
        }

        // ---- S = Q.K^T (16x32 tile) ----
        short8 kb0 = *(const short8*)&kt[cur][l15][q * 8];
        short8 kb1 = *(const short8*)&kt[cur][16 + l15][q * 8];
        f32x4 s0 = __builtin_amdgcn_mfma_f32_16x16x32_bf16(qf, kb0, (f32x4)0.f, 0, 0, 0);
        f32x4 s1 = __builtin_amdgcn_mfma_f32_16x16x32_bf16(qf, kb1, (f32x4)0.f, 0, 0, 0);

        // ---- online softmax (rows = q*4+r across 16 lanes l15) ----
        float alpha[4], p0[4], p1[4];
        bool need = false;
        #pragma unroll
        for (int r = 0; r < 4; ++r) {
            float mx = fmaxf(s0[r], s1[r]);
            #pragma unroll
            for (int d = 1; d < 16; d <<= 1) mx = fmaxf(mx, __shfl_xor(mx, d));
            float mn = fmaxf(m_i[r], mx);
            alpha[r] = __expf(m_i[r] - mn);
            need = need || (mn > m_i[r]);
            p0[r] = __expf(s0[r] - mn);
            p1[r] = __expf(s1[r] - mn);
            l_p[r] = l_p[r] * alpha[r] + p0[r] + p1[r];
            m_i[r] = mn;
        }
        if (__any(need)) {
            #pragma unroll
            for (int i = 0; i < 16; ++i) {
                acc[i][0] *= alpha[0]; acc[i][1] *= alpha[1];
                acc[i][2] *= alpha[2]; acc[i][3] *= alpha[3];
            }
        }

        // ---- P (D-frag) -> LDS -> A-frag ----
        #pragma unroll
        for (int r = 0; r < 4; ++r) {
            pb[w][q * 4 + r][l15]      = f2bf(p0[r]);
            pb[w][q * 4 + r][16 + l15] = f2bf(p1[r]);
        }
        short8 pa = *(const short8*)&pb[w][l15][q * 8];

        // ---- PV: 16 col-chunks of 16 ----
        #pragma unroll
        for (int ci = 0; ci < 16; ++ci) {
            short8 vb = *(const short8*)&vc[cur][ci * 16 + l15][q * 8];
            acc[ci] = __builtin_amdgcn_mfma_f32_16x16x32_bf16(pa, vb, acc[ci], 0, 0, 0);
        }

        // ---- write next buffer, single barrier per tile ----
        if (mt < NN / 32 - 1) {
            const int nb = cur ^ 1;
            *(short4v*)&kt[nb][krow][kseg * 4] = kreg;
            #pragma unroll
            for (int i = 0; i < 4; ++i) {
                int idx = tid + 256 * i, c = idx >> 2, seg = idx & 3;
                *(short8*)&vc[nb][c][seg * 8] = vreg[i];
            }
        }
        __syncthreads();
        cur ^= 1;
    }

    // ---- epilogue: reduce row-sums, normalize, store O[b][n][c] fp32 ----
    float inv[4];
    #pragma unroll
    for (int r = 0; r < 4; ++r) {
        float l = l_p[r];
        #pragma unroll
        for (int d = 1; d < 16; d <<= 1) l += __shfl_xor(l, d);
        inv[r] = 1.f / l;
    }
    #pragma unroll
    for (int ci = 0; ci < 16; ++ci)
        #pragma unroll
        for (int r = 0; r < 4; ++r)
            O[((size_t)b * NN + n0 + w * 16 + q * 4 + r) * CC + ci * 16 + l15] = acc[ci][r] * inv[r];
}

// ---------------- k3: epilogue transpose + residual ----------------
__global__ __launch_bounds__(256) void epilogue_kernel(
    const float* __restrict__ O, const float* __restrict__ x,
    const float* __restrict__ gamma, float* __restrict__ out)
{
    __shared__ float t[32][33];
    const int b = blockIdx.z;
    const int cb = blockIdx.y * 32;
    const int n0 = blockIdx.x * 32;
    const int tid = threadIdx.x;
    const float g = gamma[0];

    for (int idx = tid; idx < 1024; idx += 256) {
        int rr = idx >> 5, cc = idx & 31;
        t[rr][cc] = O[((size_t)b * NN + n0 + rr) * CC + cb + cc];
    }
    __syncthreads();
    for (int idx = tid; idx < 1024; idx += 256) {
        int cc = idx >> 5, rr = idx & 31;
        size_t off = ((size_t)b * CC + cb + cc) * NN + n0 + rr;
        out[off] = g * t[rr][cc] + x[off];
    }
}

extern "C" void kernel_launch(void* const* d_in, const int* in_sizes, int n_in,
                              void* d_out, int out_size, void* d_ws, size_t ws_size,
                              hipStream_t stream) {
    const float* x     = (const float*)d_in[0];
    const float* Wq    = (const float*)d_in[1];
    const float* bq    = (const float*)d_in[2];
    const float* Wk    = (const float*)d_in[3];
    const float* bk    = (const float*)d_in[4];
    const float* Wv    = (const float*)d_in[5];
    const float* bv    = (const float*)d_in[6];
    const float* gamma = (const float*)d_in[7];
    float* out = (float*)d_out;

    char* p = (char*)d_ws;
    ushort* Wb   = (ushort*)(p);                 // 320*256*2      = 163840
    float*  bias = (float*) (p + 163840);        // 320*4          = 1280
    ushort* xT   = (ushort*)(p + 165120);        // 4*4096*256*2   = 8388608
    ushort* Qb   = (ushort*)(p + 8553728);       // 4*4096*32*2    = 1048576
    ushort* Kb   = (ushort*)(p + 9602304);       // 4*4096*32*2    = 1048576
    ushort* Vb   = (ushort*)(p + 10650880);      // 4*256*4096*2   = 8388608
    float*  Ob   = (float*) (p + 19039488);      // 4*4096*256*4   = 16777216
    // total 35,816,704 B (< prior 37.7MB usage)

    pack_w_kernel<<<dim3(320), 256, 0, stream>>>(Wq, bq, Wk, bk, Wv, bv, Wb, bias);
    xpose_kernel<<<dim3(NN / 32, CC / 32, BB), 256, 0, stream>>>(x, xT);
    qkv_mfma_kernel<<<dim3(NN / 64, BB), 256, 0, stream>>>(Wb, bias, xT, Qb, Kb, Vb);
    attn_mfma_kernel<<<dim3(256), 256, 0, stream>>>(Qb, Kb, Vb, Ob);
    epilogue_kernel<<<dim3(NN / 32, CC / 32, BB), 256, 0, stream>>>(Ob, x, gamma, out);
}